// Round 4
// baseline (710.875 us; speedup 1.0000x reference)
//
#include <hip/hip_runtime.h>
#include <hip/hip_bf16.h>

#define N_TEXT 80000
#define NTOT   100000
#define NE     200000
#define EMB    256
#define HID    256
#define VMOT   17
#define MDIM   64
#define KTOK   4

typedef unsigned short u16;
typedef unsigned int   u32;
typedef short short8 __attribute__((ext_vector_type(8)));
typedef float f32x4 __attribute__((ext_vector_type(4)));

// ---------------- workspace layout (float offsets) ----------------
#define O_INVF 0                    // [NTOT]
#define O_INVR (NTOT)
#define O_POS  (2*NTOT)             // [NTOT*10]
#define O_ADJ  (12*NTOT)            // [289] (pad 512)
#define O_HTB  (12*NTOT + 512)      // u16[17*64] (pad 576 floats)
#define O_GATE (12*NTOT + 1088)
#define O_CVEC (12*NTOT + 1104)
#define O_NME  (12*NTOT + 1360)     // u16[NTOT*64]
#define O_WSW  (O_NME + NTOT*32)    // swizzled bf16 weight blob
#define ZERO_FLOATS (12*NTOT + 512)
#define Z4 (ZERO_FLOATS/4)

// blob offsets (u16), chunk = 32k x 256 cols = 8192 u16
#define OW_A 0
#define OW_B 163840
#define OW_C 172032
#define OW_D 253952
#define GA 20480
#define GB 1024
#define GC 10240
#define GD 8192
#define GTOT (GA+GB+GC+GD)

__device__ __forceinline__ u16 f2b(float f) {   // fp32 -> bf16 RNE
  unsigned u = __float_as_uint(f);
  return (u16)((u + 0x7fffu + ((u >> 16) & 1u)) >> 16);
}
__device__ __forceinline__ float b2f(u16 v) {
  return __uint_as_float(((unsigned)v) << 16);
}
__device__ __forceinline__ short8 pack8f(const float* f) {
  union { u32 u[4]; short8 s; } o;
#pragma unroll
  for (int i = 0; i < 4; i++) {
    __hip_bfloat162 b = __float22bfloat162_rn(float2{f[2*i], f[2*i+1]});
    o.u[i] = *reinterpret_cast<u32*>(&b);
  }
  return o.s;
}

// ---------------- L1: zero + swizzled weight pack ----------------
__global__ void k_prep(const float* __restrict__ nh_w, const float* __restrict__ pos_w,
                       const float* __restrict__ st_w, const float* __restrict__ pw1,
                       float* __restrict__ ws) {
  int g = blockIdx.x * blockDim.x + threadIdx.x;
  if (g < Z4) { ((float4*)ws)[g] = make_float4(0.f, 0.f, 0.f, 0.f); return; }
  g -= Z4;
  if (g >= GTOT) return;
  int l, phase;
  if (g < GA) { l = g; phase = 0; }
  else if (g < GA + GB) { l = g - GA; phase = 1; }
  else if (g < GA + GB + GC) { l = g - GA - GB; phase = 2; }
  else { l = g - GA - GB - GC; phase = 3; }
  int c = l >> 10, r = l & 1023;
  int w = r >> 8, nt = (r >> 6) & 3, ln = r & 63;
  int col = w*64 + nt*16 + (ln & 15);
  int k0  = c*32 + ((ln >> 4) << 3);
  float f[8];
#pragma unroll
  for (int j = 0; j < 8; j++) {
    int k = k0 + j;
    float v = 0.f;
    if (phase == 0)      v = nh_w[k*256 + col];
    else if (phase == 1) { if (k < 10) v = pos_w[k*256 + col];
                           else if (k >= 16 && k < 26) v = pos_w[(k-6)*256 + col]; }
    else if (phase == 2) v = st_w[k*256 + col];
    else                 v = pw1[(256 + k)*256 + col];
    f[j] = v;
  }
  ((short8*)((u16*)(ws + O_WSW)))[g] = pack8f(f);
}

// ---------------- L2: deg + DDE round-1 + motif adjacency ----------------
__global__ void k_deg_dde1_adj(const int* __restrict__ h_id, const int* __restrict__ t_id,
                               const float* __restrict__ topic,
                               const int* __restrict__ tids, const float* __restrict__ twts,
                               float* __restrict__ ws) {
  __shared__ float sadj[4*304];
  for (int i = threadIdx.x; i < 4*304; i += blockDim.x) sadj[i] = 0.f;
  __syncthreads();
  int wbase = (threadIdx.x >> 6) * 304;
  int e = blockIdx.x * blockDim.x + threadIdx.x;
  if (e < NE) {
    int h = h_id[e], t = t_id[e];
    atomicAdd(&ws[O_INVF + t], 1.0f);
    atomicAdd(&ws[O_INVR + h], 1.0f);
    float hx = topic[2*h], hy = topic[2*h + 1];
    float tx = topic[2*t], ty = topic[2*t + 1];
    if (hx != 0.f) atomicAdd(&ws[O_POS + t*10 + 2], hx);
    if (hy != 0.f) atomicAdd(&ws[O_POS + t*10 + 3], hy);
    if (tx != 0.f) atomicAdd(&ws[O_POS + h*10 + 6], tx);
    if (ty != 0.f) atomicAdd(&ws[O_POS + h*10 + 7], ty);
    int id[KTOK]; float w[KTOK];
#pragma unroll
    for (int k = 0; k < KTOK; k++) { id[k] = tids[e*KTOK + k]; w[k] = twts[e*KTOK + k]; }
#pragma unroll
    for (int i = 0; i < KTOK; i++)
#pragma unroll
      for (int j = 0; j < KTOK; j++) {
        float c = w[i] * w[j];
        if (id[i] > 0 && id[j] > 0 && c > 0.f)
          atomicAdd(&sadj[wbase + id[i]*VMOT + id[j]], c);
      }
  }
  __syncthreads();
  for (int i = threadIdx.x; i < VMOT*VMOT; i += blockDim.x) {
    float v = sadj[i] + sadj[304 + i] + sadj[608 + i] + sadj[912 + i];
    if (v != 0.f) atomicAdd(&ws[O_ADJ + i], v);
  }
}

// ---------------- L3: prep_nodes + motif GNN + gate/cvec ----------------
#define NPN_BLOCKS ((NTOT + 255)/256)
__global__ void k_pnm(const float* __restrict__ topic, const float* __restrict__ mo,
                      const float* __restrict__ gsw, const float* __restrict__ gsb,
                      const float* __restrict__ gmw, const float* __restrict__ gmb,
                      const float* __restrict__ q, const float* __restrict__ gate_w,
                      const float* __restrict__ gate_b, const float* __restrict__ pw1,
                      const float* __restrict__ pb1, float* __restrict__ ws) {
  int t = threadIdx.x;
  if (blockIdx.x < NPN_BLOCKS) {
    int n = blockIdx.x * 256 + t;
    if (n >= NTOT) return;
    float invf = 1.0f / fmaxf(ws[O_INVF + n], 1.0f);
    float invr = 1.0f / fmaxf(ws[O_INVR + n], 1.0f);
    ws[O_INVF + n] = invf;
    ws[O_INVR + n] = invr;
    float* p = &ws[O_POS + n*10];
    p[0] = topic[2*n]; p[1] = topic[2*n + 1];
    p[2] *= invf; p[3] *= invf;
    p[6] *= invr; p[7] *= invr;
  } else if (blockIdx.x == NPN_BLOCKS) {
    __shared__ float A[VMOT*VMOT];
    __shared__ float Bm[VMOT*VMOT];
    __shared__ float inv_row[VMOT];
    __shared__ float smo[VMOT*MDIM];
    __shared__ float sm[VMOT*MDIM];
    for (int i = t; i < VMOT*VMOT; i += 256) A[i] = ws[O_ADJ + i];
    for (int i = t; i < VMOT*MDIM; i += 256) smo[i] = mo[i];
    __syncthreads();
    for (int i = t; i < VMOT*VMOT; i += 256) {
      int r = i / VMOT, c = i % VMOT;
      float v = 0.5f * (A[i] + A[c*VMOT + r]) + (r == c ? 1.f : 0.f);
      if (r == 0 || c == 0) v = (r == 0 && c == 0) ? 1.f : 0.f;
      Bm[i] = v;
    }
    __syncthreads();
    if (t < VMOT) {
      float s = 0.f;
      for (int c = 0; c < VMOT; c++) s += Bm[t*VMOT + c];
      inv_row[t] = 1.f / fmaxf(s, 1e-8f);
    }
    __syncthreads();
    for (int i = t; i < VMOT*MDIM; i += 256) {
      int v = i / MDIM, d = i % MDIM;
      float s = 0.f;
      for (int u = 0; u < VMOT; u++) s += Bm[v*VMOT + u] * smo[u*MDIM + d];
      sm[i] = s * inv_row[v];
    }
    __syncthreads();
    for (int i = t; i < VMOT*MDIM; i += 256) {
      int v = i / MDIM, d = i % MDIM;
      float a = gsb[d] + gmb[d];
      for (int m = 0; m < MDIM; m++)
        a += smo[v*MDIM + m] * gsw[m*MDIM + d] + sm[v*MDIM + m] * gmw[m*MDIM + d];
      ((u16*)(ws + O_HTB))[i] = f2b(smo[i] + fmaxf(a, 0.f));
    }
  } else {
    __shared__ float sq[EMB];
    __shared__ float red[3];
    sq[t] = q[t];
    if (t < 3) red[t] = 0.f;
    __syncthreads();
    float s = pb1[t];
    for (int i = 0; i < EMB; i++) s += sq[i] * pw1[i*HID + t];
    ws[O_CVEC + t] = s;
    atomicAdd(&red[0], sq[t] * gate_w[t*3 + 0]);
    atomicAdd(&red[1], sq[t] * gate_w[t*3 + 1]);
    atomicAdd(&red[2], sq[t] * gate_w[t*3 + 2]);
    __syncthreads();
    if (t == 0) {
      float l0 = red[0] + gate_b[0], l1 = red[1] + gate_b[1], l2 = red[2] + gate_b[2];
      float mx = fmaxf(l0, fmaxf(l1, l2));
      float e0 = expf(l0 - mx), e1 = expf(l1 - mx), e2 = expf(l2 - mx);
      float inv = 1.f / (e0 + e1 + e2);
      ws[O_GATE + 0] = e0 * inv; ws[O_GATE + 1] = e1 * inv; ws[O_GATE + 2] = e2 * inv;
    }
  }
}

// ---------------- L4: DDE round-2 scatter ----------------
__global__ void k_dde2(const int* __restrict__ h_id, const int* __restrict__ t_id,
                       float* __restrict__ ws) {
  int e = blockIdx.x * blockDim.x + threadIdx.x;
  if (e >= NE) return;
  int h = h_id[e], t = t_id[e];
  float a = ws[O_POS + h*10 + 2], b = ws[O_POS + h*10 + 3];
  float c = ws[O_POS + t*10 + 6], d = ws[O_POS + t*10 + 7];
  if (a != 0.f) atomicAdd(&ws[O_POS + t*10 + 4], a);
  if (b != 0.f) atomicAdd(&ws[O_POS + t*10 + 5], b);
  if (c != 0.f) atomicAdd(&ws[O_POS + h*10 + 8], c);
  if (d != 0.f) atomicAdd(&ws[O_POS + h*10 + 9], d);
}

// ---------------- L5: round-2 scale + node motif emb (bf16) ----------------
__global__ void k_scale_nme(const int* __restrict__ nids, const float* __restrict__ nwts,
                            float* __restrict__ ws) {
  __shared__ u16 sht[VMOT*MDIM];
  for (int i = threadIdx.x; i < (VMOT*MDIM)/2; i += blockDim.x)
    ((u32*)sht)[i] = ((const u32*)(ws + O_HTB))[i];
  __syncthreads();
  int gid = blockIdx.x * blockDim.x + threadIdx.x;
  if (gid < NTOT) {
    float invf = ws[O_INVF + gid], invr = ws[O_INVR + gid];
    float* p = &ws[O_POS + gid*10];
    p[4] *= invf; p[5] *= invf;
    p[8] *= invr; p[9] *= invr;
  }
  if (gid >= NTOT * 8) return;
  int n = gid >> 3, d0 = (gid & 7) * 8;
  int4   iv = ((const int4*)nids)[n];
  float4 wv = ((const float4*)nwts)[n];
  float f[8];
#pragma unroll
  for (int j = 0; j < 8; j++) {
    f[j] = wv.x * b2f(sht[iv.x*MDIM + d0 + j]) + wv.y * b2f(sht[iv.y*MDIM + d0 + j])
         + wv.z * b2f(sht[iv.z*MDIM + d0 + j]) + wv.w * b2f(sht[iv.w*MDIM + d0 + j]);
  }
  ((short8*)((u16*)(ws + O_NME)))[gid] = pack8f(f);
}

// ---------------- L6: barrier-free MFMA edge kernel ----------------
// 64 edges x 256 cols per block, 4 waves; wave wv -> cols wv*64..+63.
// A-frags: direct per-lane global loads (fp32 -> packed bf16 in-lane).
// B-frags: direct short8 loads from swizzled blob (L2-resident).
// Gated relu terms RMW-accumulated into sF (bf16). Only 2 barriers.
__global__ __launch_bounds__(256, 3) void k_edge_mfma(
    const int* __restrict__ h_id, const int* __restrict__ r_id, const int* __restrict__ t_id,
    const float* __restrict__ ent, const float* __restrict__ rel, const float* __restrict__ nte,
    const int* __restrict__ tids, const float* __restrict__ twts,
    const float* __restrict__ nh_b, const float* __restrict__ pos_b,
    const float* __restrict__ st_b, const float* __restrict__ pw2,
    const float* __restrict__ pb2,
    const float* __restrict__ ws, float* __restrict__ out) {
  __shared__ __align__(16) u16 sF[16384];   // 32 KB: 8 k-blocks of [64 rows][32 k]
  __shared__ float sOut[64];

  const int tid = threadIdx.x;
  const int wv = tid >> 6, ln = tid & 63;
  const int lm = ln & 15, lq = ln >> 4;
  const int cb = wv * 64;
  const int e0 = blockIdx.x * 64;

  if (tid < 64) sOut[tid] = 0.f;

  int nh[4], ntl[4], nr[4];
#pragma unroll
  for (int mt = 0; mt < 4; mt++) {
    int e = e0 + mt*16 + lm;
    nh[mt] = h_id[e]; ntl[mt] = t_id[e]; nr[mt] = r_id[e];
  }
  const float g0 = ws[O_GATE + 0], g1 = ws[O_GATE + 1], g2 = ws[O_GATE + 2];
  const u16* blob = (const u16*)(ws + O_WSW);
  const u16* nmeb = (const u16*)(ws + O_NME);
  const u16* htb  = (const u16*)(ws + O_HTB);

  f32x4 acc[4][4];
#pragma unroll
  for (int mt = 0; mt < 4; mt++)
#pragma unroll
    for (int nt = 0; nt < 4; nt++) acc[mt][nt] = (f32x4){0.f, 0.f, 0.f, 0.f};

  auto bload = [&](int bc, short8 (&b)[4]) {
#pragma unroll
    for (int nt = 0; nt < 4; nt++)
      b[nt] = *(const short8*)&blob[(size_t)bc*8192 + wv*2048 + nt*512 + ln*8];
  };
  auto mfma16 = [&](short8 (&a)[4], short8 (&b)[4]) {
#pragma unroll
    for (int mt = 0; mt < 4; mt++)
#pragma unroll
      for (int nt = 0; nt < 4; nt++)
        acc[mt][nt] = __builtin_amdgcn_mfma_f32_16x16x32_bf16(a[mt], b[nt], acc[mt][nt], 0, 0, 0);
  };

  // ======== phase A: K=640 = [h_e[h] | h_e[t] | nme[h] | nme[t]] ========
#pragma unroll 2
  for (int c = 0; c < 8; c++) {           // h entity rows
    short8 a[4], b[4];
#pragma unroll
    for (int mt = 0; mt < 4; mt++) {
      int node = nh[mt];
      const float* p = ((node < N_TEXT) ? &ent[(size_t)node*256] : nte) + c*32 + lq*8;
      float4 v0 = *(const float4*)p, v1 = *(const float4*)(p + 4);
      float f[8] = {v0.x, v0.y, v0.z, v0.w, v1.x, v1.y, v1.z, v1.w};
      a[mt] = pack8f(f);
    }
    bload(c, b); mfma16(a, b);
  }
#pragma unroll 2
  for (int c = 0; c < 8; c++) {           // t entity rows
    short8 a[4], b[4];
#pragma unroll
    for (int mt = 0; mt < 4; mt++) {
      int node = ntl[mt];
      const float* p = ((node < N_TEXT) ? &ent[(size_t)node*256] : nte) + c*32 + lq*8;
      float4 v0 = *(const float4*)p, v1 = *(const float4*)(p + 4);
      float f[8] = {v0.x, v0.y, v0.z, v0.w, v1.x, v1.y, v1.z, v1.w};
      a[mt] = pack8f(f);
    }
    bload(8 + c, b); mfma16(a, b);
  }
#pragma unroll
  for (int c = 0; c < 2; c++) {           // nme[h] (already bf16)
    short8 a[4], b[4];
#pragma unroll
    for (int mt = 0; mt < 4; mt++)
      a[mt] = *(const short8*)&nmeb[(size_t)nh[mt]*64 + c*32 + lq*8];
    bload(16 + c, b); mfma16(a, b);
  }
#pragma unroll
  for (int c = 0; c < 2; c++) {           // nme[t]
    short8 a[4], b[4];
#pragma unroll
    for (int mt = 0; mt < 4; mt++)
      a[mt] = *(const short8*)&nmeb[(size_t)ntl[mt]*64 + c*32 + lq*8];
    bload(18 + c, b); mfma16(a, b);
  }
  // epilogue A: sF = g0*relu(acc + nh_b)
#pragma unroll
  for (int nt = 0; nt < 4; nt++) {
    int col = cb + nt*16 + lm;
    float bb = nh_b[col];
    int base = (col >> 5)*2048 + (col & 31);
#pragma unroll
    for (int mt = 0; mt < 4; mt++)
#pragma unroll
      for (int r = 0; r < 4; r++) {
        sF[base + (mt*16 + lq*4 + r)*32] = f2b(g0 * fmaxf(acc[mt][nt][r] + bb, 0.f));
        acc[mt][nt][r] = 0.f;
      }
  }

  // ======== phase B: K=32 = [pos[h](10) pad6 | pos[t](10) pad6] ========
  {
    short8 a[4], b[4];
#pragma unroll
    for (int mt = 0; mt < 4; mt++) {
      int node = (lq < 2) ? nh[mt] : ntl[mt];
      int k0 = (lq & 1) * 8;
      const float* p = &ws[O_POS + (size_t)node*10 + k0];   // 8B-aligned
      float2 v0 = *(const float2*)p,       v1 = *(const float2*)(p + 2);
      float2 v2 = *(const float2*)(p + 4), v3 = *(const float2*)(p + 6);
      float f[8] = {v0.x, v0.y, v1.x, v1.y, v2.x, v2.y, v3.x, v3.y};
#pragma unroll
      for (int j = 0; j < 8; j++) if (k0 + j >= 10) f[j] = 0.f;
      a[mt] = pack8f(f);
    }
    bload((OW_B/8192), b); mfma16(a, b);
  }
#pragma unroll
  for (int nt = 0; nt < 4; nt++) {
    int col = cb + nt*16 + lm;
    float bb = pos_b[col];
    int base = (col >> 5)*2048 + (col & 31);
#pragma unroll
    for (int mt = 0; mt < 4; mt++)
#pragma unroll
      for (int r = 0; r < 4; r++) {
        u16* p = &sF[base + (mt*16 + lq*4 + r)*32];
        *p = f2b(b2f(*p) + g1 * fmaxf(acc[mt][nt][r] + bb, 0.f));
        acc[mt][nt][r] = 0.f;
      }
  }

  // ======== phase C: K=320 = [rel[r] | triple_motif_emb] ========
#pragma unroll 2
  for (int c = 0; c < 8; c++) {           // relation rows
    short8 a[4], b[4];
#pragma unroll
    for (int mt = 0; mt < 4; mt++) {
      const float* p = &rel[(size_t)nr[mt]*256 + c*32 + lq*8];
      float4 v0 = *(const float4*)p, v1 = *(const float4*)(p + 4);
      float f[8] = {v0.x, v0.y, v0.z, v0.w, v1.x, v1.y, v1.z, v1.w};
      a[mt] = pack8f(f);
    }
    bload(OW_C/8192 + c, b); mfma16(a, b);
  }
#pragma unroll
  for (int c = 0; c < 2; c++) {           // triple motif emb (inline from ht)
    short8 a[4], b[4];
#pragma unroll
    for (int mt = 0; mt < 4; mt++) {
      int e = e0 + mt*16 + lm;
      int4   iv  = ((const int4*)tids)[e];
      float4 wv4 = ((const float4*)twts)[e];
      int d0 = c*32 + lq*8;
      short8 h0 = *(const short8*)&htb[iv.x*64 + d0];
      short8 h1 = *(const short8*)&htb[iv.y*64 + d0];
      short8 h2 = *(const short8*)&htb[iv.z*64 + d0];
      short8 h3 = *(const short8*)&htb[iv.w*64 + d0];
      float f[8];
#pragma unroll
      for (int j = 0; j < 8; j++)
        f[j] = wv4.x * b2f((u16)h0[j]) + wv4.y * b2f((u16)h1[j])
             + wv4.z * b2f((u16)h2[j]) + wv4.w * b2f((u16)h3[j]);
      a[mt] = pack8f(f);
    }
    bload(OW_C/8192 + 8 + c, b); mfma16(a, b);
  }
#pragma unroll
  for (int nt = 0; nt < 4; nt++) {
    int col = cb + nt*16 + lm;
    float bb = st_b[col];
    int base = (col >> 5)*2048 + (col & 31);
#pragma unroll
    for (int mt = 0; mt < 4; mt++)
#pragma unroll
      for (int r = 0; r < 4; r++) {
        u16* p = &sF[base + (mt*16 + lq*4 + r)*32];
        *p = f2b(b2f(*p) + g2 * fmaxf(acc[mt][nt][r] + bb, 0.f));
        acc[mt][nt][r] = 0.f;
      }
  }

  __syncthreads();   // sF complete (also covers sOut init)

  // ======== phase D: hidden = fused @ pw1[256:512] ========
#pragma unroll 2
  for (int c = 0; c < 8; c++) {
    short8 a[4], b[4];
#pragma unroll
    for (int mt = 0; mt < 4; mt++)
      a[mt] = *(const short8*)&sF[c*2048 + (mt*16 + lm)*32 + lq*8];
    bload(OW_D/8192 + c, b); mfma16(a, b);
  }

  // ======== epilogue: out = relu(hidden + cvec) @ pw2 + pb2 ========
  {
    float cv[4], p2[4];
#pragma unroll
    for (int nt = 0; nt < 4; nt++) {
      int col = cb + nt*16 + lm;
      cv[nt] = ws[O_CVEC + col];
      p2[nt] = pw2[col];
    }
#pragma unroll
    for (int mt = 0; mt < 4; mt++)
#pragma unroll
      for (int r = 0; r < 4; r++) {
        float s = 0.f;
#pragma unroll
        for (int nt = 0; nt < 4; nt++)
          s += fmaxf(acc[mt][nt][r] + cv[nt], 0.f) * p2[nt];
#pragma unroll
        for (int off = 1; off < 16; off <<= 1)
          s += __shfl_xor(s, off, 64);
        if (lm == 0) atomicAdd(&sOut[mt*16 + lq*4 + r], s);
      }
  }
  __syncthreads();
  if (tid < 64) out[e0 + tid] = sOut[tid] + pb2[0];
}

// ---------------- launch ----------------
extern "C" void kernel_launch(void* const* d_in, const int* in_sizes, int n_in,
                              void* d_out, int out_size, void* d_ws, size_t ws_size,
                              hipStream_t stream) {
  (void)in_sizes; (void)n_in; (void)out_size; (void)ws_size;
  const int*   h_id   = (const int*)  d_in[0];
  const int*   r_id   = (const int*)  d_in[1];
  const int*   t_id   = (const int*)  d_in[2];
  const float* q      = (const float*)d_in[3];
  const float* ent    = (const float*)d_in[4];
  const float* rel    = (const float*)d_in[6];
  const float* topic  = (const float*)d_in[7];
  const int*   nids   = (const int*)  d_in[8];
  const float* nwts   = (const float*)d_in[9];
  const int*   tids   = (const int*)  d_in[10];
  const float* twts   = (const float*)d_in[11];
  const float* nte    = (const float*)d_in[12];
  const float* mo     = (const float*)d_in[13];
  const float* gsw    = (const float*)d_in[14];
  const float* gsb    = (const float*)d_in[15];
  const float* gmw    = (const float*)d_in[16];
  const float* gmb    = (const float*)d_in[17];
  const float* nh_b   = (const float*)d_in[19];
  const float* pos_w  = (const float*)d_in[20];
  const float* pos_b  = (const float*)d_in[21];
  const float* st_w   = (const float*)d_in[22];
  const float* st_b   = (const float*)d_in[23];
  const float* gate_w = (const float*)d_in[24];
  const float* gate_b = (const float*)d_in[25];
  const float* pw1    = (const float*)d_in[26];
  const float* pb1    = (const float*)d_in[27];
  const float* pw2    = (const float*)d_in[28];
  const float* pb2    = (const float*)d_in[29];
  const float* nh_w   = (const float*)d_in[18];
  float* ws  = (float*)d_ws;
  float* out = (float*)d_out;

  k_prep<<<(Z4 + GTOT + 255)/256, 256, 0, stream>>>(nh_w, pos_w, st_w, pw1, ws);
  k_deg_dde1_adj<<<(NE + 255)/256, 256, 0, stream>>>(h_id, t_id, topic, tids, twts, ws);
  k_pnm<<<NPN_BLOCKS + 2, 256, 0, stream>>>(topic, mo, gsw, gsb, gmw, gmb,
                                            q, gate_w, gate_b, pw1, pb1, ws);
  k_dde2<<<(NE + 255)/256, 256, 0, stream>>>(h_id, t_id, ws);
  k_scale_nme<<<(NTOT*8 + 255)/256, 256, 0, stream>>>(nids, nwts, ws);
  k_edge_mfma<<<NE/64, 256, 0, stream>>>(h_id, r_id, t_id, ent, rel, nte, tids, twts,
                                         nh_b, pos_b, st_b, pw2, pb2, ws, out);
}

// Round 5
// 475.392 us; speedup vs baseline: 1.4953x; 1.4953x over previous
//
#include <hip/hip_runtime.h>
#include <hip/hip_bf16.h>

#define N_TEXT 80000
#define NTOT   100000
#define NE     200000
#define EMB    256
#define HID    256
#define VMOT   17
#define MDIM   64
#define KTOK   4

typedef unsigned short u16;
typedef unsigned int   u32;
typedef short short8 __attribute__((ext_vector_type(8)));
typedef float f32x4 __attribute__((ext_vector_type(4)));

// ---------------- workspace layout (float offsets) ----------------
#define O_INVF 0                    // [NTOT]
#define O_INVR (NTOT)
#define O_POS  (2*NTOT)             // [NTOT*10]
#define O_ADJ  (12*NTOT)            // [289] (pad 512)
#define O_HTB  (12*NTOT + 512)      // u16[17*64] (pad 576 floats)
#define O_GATE (12*NTOT + 1088)
#define O_CVEC (12*NTOT + 1104)
#define O_NME  (12*NTOT + 1360)     // u16[NTOT*64]
#define O_WSW  (O_NME + NTOT*32)    // swizzled bf16 weight blob
#define ZERO_FLOATS (12*NTOT + 512)
#define Z4 (ZERO_FLOATS/4)

// blob offsets (u16), chunk = 32k x 256 cols = 8192 u16
// chunk index: A=0..19, B=20, C=21..30, D=31..38
#define OW_A 0
#define OW_B 163840
#define OW_C 172032
#define OW_D 253952
#define GA 20480
#define GB 1024
#define GC 10240
#define GD 8192
#define GTOT (GA+GB+GC+GD)

__device__ __forceinline__ u16 f2b(float f) {   // fp32 -> bf16 RNE
  unsigned u = __float_as_uint(f);
  return (u16)((u + 0x7fffu + ((u >> 16) & 1u)) >> 16);
}
__device__ __forceinline__ float b2f(u16 v) {
  return __uint_as_float(((unsigned)v) << 16);
}
__device__ __forceinline__ short8 pack8f(const float* f) {
  union { u32 u[4]; short8 s; } o;
#pragma unroll
  for (int i = 0; i < 4; i++) {
    __hip_bfloat162 b = __float22bfloat162_rn(float2{f[2*i], f[2*i+1]});
    o.u[i] = *reinterpret_cast<u32*>(&b);
  }
  return o.s;
}

// ---------------- L1: zero + swizzled weight pack ----------------
__global__ void k_prep(const float* __restrict__ nh_w, const float* __restrict__ pos_w,
                       const float* __restrict__ st_w, const float* __restrict__ pw1,
                       float* __restrict__ ws) {
  int g = blockIdx.x * blockDim.x + threadIdx.x;
  if (g < Z4) { ((float4*)ws)[g] = make_float4(0.f, 0.f, 0.f, 0.f); return; }
  g -= Z4;
  if (g >= GTOT) return;
  int l, phase;
  if (g < GA) { l = g; phase = 0; }
  else if (g < GA + GB) { l = g - GA; phase = 1; }
  else if (g < GA + GB + GC) { l = g - GA - GB; phase = 2; }
  else { l = g - GA - GB - GC; phase = 3; }
  int c = l >> 10, r = l & 1023;
  int w = r >> 8, nt = (r >> 6) & 3, ln = r & 63;
  int col = w*64 + nt*16 + (ln & 15);
  int k0  = c*32 + ((ln >> 4) << 3);
  float f[8];
#pragma unroll
  for (int j = 0; j < 8; j++) {
    int k = k0 + j;
    float v = 0.f;
    if (phase == 0)      v = nh_w[k*256 + col];
    else if (phase == 1) { if (k < 10) v = pos_w[k*256 + col];
                           else if (k >= 16 && k < 26) v = pos_w[(k-6)*256 + col]; }
    else if (phase == 2) v = st_w[k*256 + col];
    else                 v = pw1[(256 + k)*256 + col];
    f[j] = v;
  }
  ((short8*)((u16*)(ws + O_WSW)))[g] = pack8f(f);
}

// ---------------- L2: deg + DDE round-1 + motif adjacency ----------------
__global__ void k_deg_dde1_adj(const int* __restrict__ h_id, const int* __restrict__ t_id,
                               const float* __restrict__ topic,
                               const int* __restrict__ tids, const float* __restrict__ twts,
                               float* __restrict__ ws) {
  __shared__ float sadj[4*304];
  for (int i = threadIdx.x; i < 4*304; i += blockDim.x) sadj[i] = 0.f;
  __syncthreads();
  int wbase = (threadIdx.x >> 6) * 304;
  int e = blockIdx.x * blockDim.x + threadIdx.x;
  if (e < NE) {
    int h = h_id[e], t = t_id[e];
    atomicAdd(&ws[O_INVF + t], 1.0f);
    atomicAdd(&ws[O_INVR + h], 1.0f);
    float hx = topic[2*h], hy = topic[2*h + 1];
    float tx = topic[2*t], ty = topic[2*t + 1];
    if (hx != 0.f) atomicAdd(&ws[O_POS + t*10 + 2], hx);
    if (hy != 0.f) atomicAdd(&ws[O_POS + t*10 + 3], hy);
    if (tx != 0.f) atomicAdd(&ws[O_POS + h*10 + 6], tx);
    if (ty != 0.f) atomicAdd(&ws[O_POS + h*10 + 7], ty);
    int id[KTOK]; float w[KTOK];
#pragma unroll
    for (int k = 0; k < KTOK; k++) { id[k] = tids[e*KTOK + k]; w[k] = twts[e*KTOK + k]; }
#pragma unroll
    for (int i = 0; i < KTOK; i++)
#pragma unroll
      for (int j = 0; j < KTOK; j++) {
        float c = w[i] * w[j];
        if (id[i] > 0 && id[j] > 0 && c > 0.f)
          atomicAdd(&sadj[wbase + id[i]*VMOT + id[j]], c);
      }
  }
  __syncthreads();
  for (int i = threadIdx.x; i < VMOT*VMOT; i += blockDim.x) {
    float v = sadj[i] + sadj[304 + i] + sadj[608 + i] + sadj[912 + i];
    if (v != 0.f) atomicAdd(&ws[O_ADJ + i], v);
  }
}

// ---------------- L3: prep_nodes + motif GNN + gate/cvec ----------------
#define NPN_BLOCKS ((NTOT + 255)/256)
__global__ void k_pnm(const float* __restrict__ topic, const float* __restrict__ mo,
                      const float* __restrict__ gsw, const float* __restrict__ gsb,
                      const float* __restrict__ gmw, const float* __restrict__ gmb,
                      const float* __restrict__ q, const float* __restrict__ gate_w,
                      const float* __restrict__ gate_b, const float* __restrict__ pw1,
                      const float* __restrict__ pb1, float* __restrict__ ws) {
  int t = threadIdx.x;
  if (blockIdx.x < NPN_BLOCKS) {
    int n = blockIdx.x * 256 + t;
    if (n >= NTOT) return;
    float invf = 1.0f / fmaxf(ws[O_INVF + n], 1.0f);
    float invr = 1.0f / fmaxf(ws[O_INVR + n], 1.0f);
    ws[O_INVF + n] = invf;
    ws[O_INVR + n] = invr;
    float* p = &ws[O_POS + n*10];
    p[0] = topic[2*n]; p[1] = topic[2*n + 1];
    p[2] *= invf; p[3] *= invf;
    p[6] *= invr; p[7] *= invr;
  } else if (blockIdx.x == NPN_BLOCKS) {
    __shared__ float A[VMOT*VMOT];
    __shared__ float Bm[VMOT*VMOT];
    __shared__ float inv_row[VMOT];
    __shared__ float smo[VMOT*MDIM];
    __shared__ float sm[VMOT*MDIM];
    for (int i = t; i < VMOT*VMOT; i += 256) A[i] = ws[O_ADJ + i];
    for (int i = t; i < VMOT*MDIM; i += 256) smo[i] = mo[i];
    __syncthreads();
    for (int i = t; i < VMOT*VMOT; i += 256) {
      int r = i / VMOT, c = i % VMOT;
      float v = 0.5f * (A[i] + A[c*VMOT + r]) + (r == c ? 1.f : 0.f);
      if (r == 0 || c == 0) v = (r == 0 && c == 0) ? 1.f : 0.f;
      Bm[i] = v;
    }
    __syncthreads();
    if (t < VMOT) {
      float s = 0.f;
      for (int c = 0; c < VMOT; c++) s += Bm[t*VMOT + c];
      inv_row[t] = 1.f / fmaxf(s, 1e-8f);
    }
    __syncthreads();
    for (int i = t; i < VMOT*MDIM; i += 256) {
      int v = i / MDIM, d = i % MDIM;
      float s = 0.f;
      for (int u = 0; u < VMOT; u++) s += Bm[v*VMOT + u] * smo[u*MDIM + d];
      sm[i] = s * inv_row[v];
    }
    __syncthreads();
    for (int i = t; i < VMOT*MDIM; i += 256) {
      int v = i / MDIM, d = i % MDIM;
      float a = gsb[d] + gmb[d];
      for (int m = 0; m < MDIM; m++)
        a += smo[v*MDIM + m] * gsw[m*MDIM + d] + sm[v*MDIM + m] * gmw[m*MDIM + d];
      ((u16*)(ws + O_HTB))[i] = f2b(smo[i] + fmaxf(a, 0.f));
    }
  } else {
    __shared__ float sq[EMB];
    __shared__ float red[3];
    sq[t] = q[t];
    if (t < 3) red[t] = 0.f;
    __syncthreads();
    float s = pb1[t];
    for (int i = 0; i < EMB; i++) s += sq[i] * pw1[i*HID + t];
    ws[O_CVEC + t] = s;
    atomicAdd(&red[0], sq[t] * gate_w[t*3 + 0]);
    atomicAdd(&red[1], sq[t] * gate_w[t*3 + 1]);
    atomicAdd(&red[2], sq[t] * gate_w[t*3 + 2]);
    __syncthreads();
    if (t == 0) {
      float l0 = red[0] + gate_b[0], l1 = red[1] + gate_b[1], l2 = red[2] + gate_b[2];
      float mx = fmaxf(l0, fmaxf(l1, l2));
      float e0 = expf(l0 - mx), e1 = expf(l1 - mx), e2 = expf(l2 - mx);
      float inv = 1.f / (e0 + e1 + e2);
      ws[O_GATE + 0] = e0 * inv; ws[O_GATE + 1] = e1 * inv; ws[O_GATE + 2] = e2 * inv;
    }
  }
}

// ---------------- L4: DDE round-2 scatter ----------------
__global__ void k_dde2(const int* __restrict__ h_id, const int* __restrict__ t_id,
                       float* __restrict__ ws) {
  int e = blockIdx.x * blockDim.x + threadIdx.x;
  if (e >= NE) return;
  int h = h_id[e], t = t_id[e];
  float a = ws[O_POS + h*10 + 2], b = ws[O_POS + h*10 + 3];
  float c = ws[O_POS + t*10 + 6], d = ws[O_POS + t*10 + 7];
  if (a != 0.f) atomicAdd(&ws[O_POS + t*10 + 4], a);
  if (b != 0.f) atomicAdd(&ws[O_POS + t*10 + 5], b);
  if (c != 0.f) atomicAdd(&ws[O_POS + h*10 + 8], c);
  if (d != 0.f) atomicAdd(&ws[O_POS + h*10 + 9], d);
}

// ---------------- L5: round-2 scale + node motif emb (bf16) ----------------
__global__ void k_scale_nme(const int* __restrict__ nids, const float* __restrict__ nwts,
                            float* __restrict__ ws) {
  __shared__ u16 sht[VMOT*MDIM];
  for (int i = threadIdx.x; i < (VMOT*MDIM)/2; i += blockDim.x)
    ((u32*)sht)[i] = ((const u32*)(ws + O_HTB))[i];
  __syncthreads();
  int gid = blockIdx.x * blockDim.x + threadIdx.x;
  if (gid < NTOT) {
    float invf = ws[O_INVF + gid], invr = ws[O_INVR + gid];
    float* p = &ws[O_POS + gid*10];
    p[4] *= invf; p[5] *= invf;
    p[8] *= invr; p[9] *= invr;
  }
  if (gid >= NTOT * 8) return;
  int n = gid >> 3, d0 = (gid & 7) * 8;
  int4   iv = ((const int4*)nids)[n];
  float4 wv = ((const float4*)nwts)[n];
  float f[8];
#pragma unroll
  for (int j = 0; j < 8; j++) {
    f[j] = wv.x * b2f(sht[iv.x*MDIM + d0 + j]) + wv.y * b2f(sht[iv.y*MDIM + d0 + j])
         + wv.z * b2f(sht[iv.z*MDIM + d0 + j]) + wv.w * b2f(sht[iv.w*MDIM + d0 + j]);
  }
  ((short8*)((u16*)(ws + O_NME)))[gid] = pack8f(f);
}

// ---------------- L6: MFMA edge kernel (staged A, direct-global B) ----------
// 64 edges x 256 cols per block, 4 waves; wave wv -> cols wv*64..+63.
// A staged cooperatively (coalesced, 1x per block) into sX; B-fragments
// loaded per-wave straight from the swizzled blob (disjoint slices, L2-hot).
// Gated relu accumulated into sF (bf16). LDS ~37 KB -> 4 blocks/CU.
__global__ __launch_bounds__(256, 4) void k_edge_mfma(
    const int* __restrict__ h_id, const int* __restrict__ r_id, const int* __restrict__ t_id,
    const float* __restrict__ ent, const float* __restrict__ rel, const float* __restrict__ nte,
    const int* __restrict__ tids, const float* __restrict__ twts,
    const float* __restrict__ nh_b, const float* __restrict__ pos_b,
    const float* __restrict__ st_b, const float* __restrict__ pw2,
    const float* __restrict__ pb2,
    const float* __restrict__ ws, float* __restrict__ out) {
  __shared__ __align__(16) u16 sX[64*32];      // 4 KB  (chunk: 64 edges x 32 k)
  __shared__ __align__(16) u16 sF[16384];      // 32 KB (8 col-blocks x 64 rows x 32)
  __shared__ float sOut[64];
  __shared__ int sh[64], stt[64], sr[64];

  const int tid = threadIdx.x;
  const int wv = tid >> 6, ln = tid & 63;
  const int lm = ln & 15, lq = ln >> 4;
  const int cb = wv * 64;
  const int e0 = blockIdx.x * 64;
  const int srow = tid >> 2, sks = tid & 3;    // staging: row, 8-k segment

  if (tid < 64) {
    sh[tid]  = h_id[e0 + tid];
    stt[tid] = t_id[e0 + tid];
    sr[tid]  = r_id[e0 + tid];
    sOut[tid] = 0.f;
  }
  const float g0 = ws[O_GATE + 0], g1 = ws[O_GATE + 1], g2 = ws[O_GATE + 2];
  const u16* blob = (const u16*)(ws + O_WSW);
  const u16* nmeb = (const u16*)(ws + O_NME);
  const u16* htb  = (const u16*)(ws + O_HTB);
  const int4   tiv = ((const int4*)tids)[e0 + srow];
  const float4 twv = ((const float4*)twts)[e0 + srow];
  __syncthreads();

  f32x4 acc[4][4];
#pragma unroll
  for (int mt = 0; mt < 4; mt++)
#pragma unroll
    for (int nt = 0; nt < 4; nt++) acc[mt][nt] = (f32x4){0.f, 0.f, 0.f, 0.f};

#define MFMA_STEP(bc)                                                    \
  { short8 a[4], b[4];                                                   \
    _Pragma("unroll")                                                    \
    for (int nt = 0; nt < 4; nt++)                                       \
      b[nt] = *(const short8*)&blob[(bc)*8192 + wv*2048 + nt*512 + ln*8];\
    _Pragma("unroll")                                                    \
    for (int mt = 0; mt < 4; mt++)                                       \
      a[mt] = *(const short8*)&sX[(mt*16 + lm)*32 + lq*8];               \
    _Pragma("unroll")                                                    \
    for (int mt = 0; mt < 4; mt++)                                       \
      _Pragma("unroll")                                                  \
      for (int nt = 0; nt < 4; nt++)                                     \
        acc[mt][nt] = __builtin_amdgcn_mfma_f32_16x16x32_bf16(a[mt], b[nt], acc[mt][nt], 0, 0, 0); }

  // ======== phase A: K=640 = [h_e[h] | h_e[t] | nme[h] | nme[t]] ========
  {
    float4 fa, fb; short8 xs;
    auto loadA = [&](int kc) {
      int kk = kc + sks*8;
      if (kk < 512) {
        int node = (kk < 256) ? sh[srow] : stt[srow];
        int k2 = kk & 255;
        const float* src = (node < N_TEXT) ? &ent[(size_t)node*256 + k2] : &nte[k2];
        fa = *(const float4*)src; fb = *(const float4*)(src + 4);
      } else {
        int node = (kk < 576) ? sh[srow] : stt[srow];
        xs = *(const short8*)&nmeb[(size_t)node*64 + ((kk - 512) & 63)];
      }
    };
    loadA(0);
#pragma unroll 2
    for (int c = 0; c < 20; c++) {
      if (c < 16) {
        float f[8] = {fa.x, fa.y, fa.z, fa.w, fb.x, fb.y, fb.z, fb.w};
        *(short8*)&sX[srow*32 + sks*8] = pack8f(f);
      } else {
        *(short8*)&sX[srow*32 + sks*8] = xs;
      }
      __syncthreads();
      if (c < 19) loadA((c+1)*32);
      MFMA_STEP(c);
      __syncthreads();
    }
  }
  // epilogue A: sF = g0*relu(acc + nh_b)
#pragma unroll
  for (int nt = 0; nt < 4; nt++) {
    int col = cb + nt*16 + lm;
    float bb = nh_b[col];
    int base = (col >> 5)*2048 + (col & 31);
#pragma unroll
    for (int mt = 0; mt < 4; mt++)
#pragma unroll
      for (int r = 0; r < 4; r++) {
        sF[base + (mt*16 + lq*4 + r)*32] = f2b(g0 * fmaxf(acc[mt][nt][r] + bb, 0.f));
        acc[mt][nt][r] = 0.f;
      }
  }

  // ======== phase B: K=32 = [pos[h](10) pad6 | pos[t](10) pad6] ========
  {
    int node_h = sh[srow], node_t = stt[srow];
    float f[8];
#pragma unroll
    for (int j = 0; j < 8; j++) {
      int kk = sks*8 + j;
      float v = 0.f;
      if (kk < 10) v = ws[O_POS + (size_t)node_h*10 + kk];
      else if (kk >= 16 && kk < 26) v = ws[O_POS + (size_t)node_t*10 + kk - 16];
      f[j] = v;
    }
    *(short8*)&sX[srow*32 + sks*8] = pack8f(f);
    __syncthreads();
    MFMA_STEP(20);
    __syncthreads();
  }
#pragma unroll
  for (int nt = 0; nt < 4; nt++) {
    int col = cb + nt*16 + lm;
    float bb = pos_b[col];
    int base = (col >> 5)*2048 + (col & 31);
#pragma unroll
    for (int mt = 0; mt < 4; mt++)
#pragma unroll
      for (int r = 0; r < 4; r++) {
        u16* p = &sF[base + (mt*16 + lq*4 + r)*32];
        *p = f2b(b2f(*p) + g1 * fmaxf(acc[mt][nt][r] + bb, 0.f));
        acc[mt][nt][r] = 0.f;
      }
  }

  // ======== phase C: K=320 = [rel[r] | triple_motif_emb] ========
  {
    float4 fa, fb; short8 hs0, hs1, hs2, hs3;
    auto loadC = [&](int kc) {
      int kk = kc + sks*8;
      if (kk < 256) {
        const float* src = &rel[(size_t)sr[srow]*256 + kk];
        fa = *(const float4*)src; fb = *(const float4*)(src + 4);
      } else {
        int d0 = kk - 256;
        hs0 = *(const short8*)&htb[tiv.x*64 + d0];
        hs1 = *(const short8*)&htb[tiv.y*64 + d0];
        hs2 = *(const short8*)&htb[tiv.z*64 + d0];
        hs3 = *(const short8*)&htb[tiv.w*64 + d0];
      }
    };
    loadC(0);
#pragma unroll 2
    for (int c = 0; c < 10; c++) {
      if (c < 8) {
        float f[8] = {fa.x, fa.y, fa.z, fa.w, fb.x, fb.y, fb.z, fb.w};
        *(short8*)&sX[srow*32 + sks*8] = pack8f(f);
      } else {
        float f[8];
#pragma unroll
        for (int j = 0; j < 8; j++)
          f[j] = twv.x * b2f((u16)hs0[j]) + twv.y * b2f((u16)hs1[j])
               + twv.z * b2f((u16)hs2[j]) + twv.w * b2f((u16)hs3[j]);
        *(short8*)&sX[srow*32 + sks*8] = pack8f(f);
      }
      __syncthreads();
      if (c < 9) loadC((c+1)*32);
      MFMA_STEP(21 + c);
      __syncthreads();
    }
  }
#pragma unroll
  for (int nt = 0; nt < 4; nt++) {
    int col = cb + nt*16 + lm;
    float bb = st_b[col];
    int base = (col >> 5)*2048 + (col & 31);
#pragma unroll
    for (int mt = 0; mt < 4; mt++)
#pragma unroll
      for (int r = 0; r < 4; r++) {
        u16* p = &sF[base + (mt*16 + lq*4 + r)*32];
        *p = f2b(b2f(*p) + g2 * fmaxf(acc[mt][nt][r] + bb, 0.f));
        acc[mt][nt][r] = 0.f;
      }
  }

  __syncthreads();   // sF complete

  // ======== phase D: hidden = fused @ pw1[256:512] (no barriers inside) ====
#pragma unroll 2
  for (int c = 0; c < 8; c++) {
    short8 a[4], b[4];
#pragma unroll
    for (int nt = 0; nt < 4; nt++)
      b[nt] = *(const short8*)&blob[(31 + c)*8192 + wv*2048 + nt*512 + ln*8];
#pragma unroll
    for (int mt = 0; mt < 4; mt++)
      a[mt] = *(const short8*)&sF[c*2048 + (mt*16 + lm)*32 + lq*8];
#pragma unroll
    for (int mt = 0; mt < 4; mt++)
#pragma unroll
      for (int nt = 0; nt < 4; nt++)
        acc[mt][nt] = __builtin_amdgcn_mfma_f32_16x16x32_bf16(a[mt], b[nt], acc[mt][nt], 0, 0, 0);
  }

  // ======== epilogue: out = relu(hidden + cvec) @ pw2 + pb2 ========
  {
    float cv[4], p2[4];
#pragma unroll
    for (int nt = 0; nt < 4; nt++) {
      int col = cb + nt*16 + lm;
      cv[nt] = ws[O_CVEC + col];
      p2[nt] = pw2[col];
    }
#pragma unroll
    for (int mt = 0; mt < 4; mt++)
#pragma unroll
      for (int r = 0; r < 4; r++) {
        float s = 0.f;
#pragma unroll
        for (int nt = 0; nt < 4; nt++)
          s += fmaxf(acc[mt][nt][r] + cv[nt], 0.f) * p2[nt];
#pragma unroll
        for (int off = 1; off < 16; off <<= 1)
          s += __shfl_xor(s, off, 64);
        if (lm == 0) atomicAdd(&sOut[mt*16 + lq*4 + r], s);
      }
  }
  __syncthreads();
  if (tid < 64) out[e0 + tid] = sOut[tid] + pb2[0];
#undef MFMA_STEP
}

// ---------------- launch ----------------
extern "C" void kernel_launch(void* const* d_in, const int* in_sizes, int n_in,
                              void* d_out, int out_size, void* d_ws, size_t ws_size,
                              hipStream_t stream) {
  (void)in_sizes; (void)n_in; (void)out_size; (void)ws_size;
  const int*   h_id   = (const int*)  d_in[0];
  const int*   r_id   = (const int*)  d_in[1];
  const int*   t_id   = (const int*)  d_in[2];
  const float* q      = (const float*)d_in[3];
  const float* ent    = (const float*)d_in[4];
  const float* rel    = (const float*)d_in[6];
  const float* topic  = (const float*)d_in[7];
  const int*   nids   = (const int*)  d_in[8];
  const float* nwts   = (const float*)d_in[9];
  const int*   tids   = (const int*)  d_in[10];
  const float* twts   = (const float*)d_in[11];
  const float* nte    = (const float*)d_in[12];
  const float* mo     = (const float*)d_in[13];
  const float* gsw    = (const float*)d_in[14];
  const float* gsb    = (const float*)d_in[15];
  const float* gmw    = (const float*)d_in[16];
  const float* gmb    = (const float*)d_in[17];
  const float* nh_w   = (const float*)d_in[18];
  const float* nh_b   = (const float*)d_in[19];
  const float* pos_w  = (const float*)d_in[20];
  const float* pos_b  = (const float*)d_in[21];
  const float* st_w   = (const float*)d_in[22];
  const float* st_b   = (const float*)d_in[23];
  const float* gate_w = (const float*)d_in[24];
  const float* gate_b = (const float*)d_in[25];
  const float* pw1    = (const float*)d_in[26];
  const float* pb1    = (const float*)d_in[27];
  const float* pw2    = (const float*)d_in[28];
  const float* pb2    = (const float*)d_in[29];
  float* ws  = (float*)d_ws;
  float* out = (float*)d_out;

  k_prep<<<(Z4 + GTOT + 255)/256, 256, 0, stream>>>(nh_w, pos_w, st_w, pw1, ws);
  k_deg_dde1_adj<<<(NE + 255)/256, 256, 0, stream>>>(h_id, t_id, topic, tids, twts, ws);
  k_pnm<<<NPN_BLOCKS + 2, 256, 0, stream>>>(topic, mo, gsw, gsb, gmw, gmb,
                                            q, gate_w, gate_b, pw1, pb1, ws);
  k_dde2<<<(NE + 255)/256, 256, 0, stream>>>(h_id, t_id, ws);
  k_scale_nme<<<(NTOT*8 + 255)/256, 256, 0, stream>>>(nids, nwts, ws);
  k_edge_mfma<<<NE/64, 256, 0, stream>>>(h_id, r_id, t_id, ent, rel, nte, tids, twts,
                                         nh_b, pos_b, st_b, pw2, pb2, ws, out);
}